// Round 4
// baseline (633.695 us; speedup 1.0000x reference)
//
#include <hip/hip_runtime.h>
#include <hip/hip_bf16.h>
#include <stdint.h>

#define N_NODES 500000
#define N_EDGES 600000
#define N_GRAPHS 4096
#define XD 128
#define HD 128
#define ZD 64
#define BROWS 64                 // nodes per bucket
#define NBUCKETS 7813            // ceil(N_NODES/64)
#define CAP 160                  // bucket capacity (lambda=76.8, +9.5 sigma)

// float-offsets in ws
#define OFF_CUR   0ull           // 8192 ints
#define OFF_SUMS  8192ull        // 524288 f
#define OFF_BUF   532480ull      // uint2 x NBUCKETS*CAP = 2500160 u32
#define OFF_CNT   3032640ull     // 4096 f
#define OFF_AT    3036736ull     // 524288 f
#define OFF_STATS 3561024ull     // 256 f
#define OFF_WT    3561280ull     // 16384 u32 (bf16 panels: [0]=Wnbr, [8192]=Wself)

typedef __attribute__((ext_vector_type(8))) short bf16x8;
typedef __attribute__((ext_vector_type(4))) float f32x4;

__device__ inline uint32_t pk_bf16(float lo, float hi) {
  uint32_t ul = __float_as_uint(lo); ul += 0x7fffu + ((ul >> 16) & 1u);
  uint32_t uh = __float_as_uint(hi); uh += 0x7fffu + ((uh >> 16) & 1u);
  return (ul >> 16) | (uh & 0xffff0000u);
}

// ---------------- K0: preconvert W to bf16 panels, [n][k2] plain layout ----------------
__global__ void wprep_kernel(const float* __restrict__ Wnbr, const float* __restrict__ Wself,
                             uint32_t* __restrict__ wt) {
  const float* __restrict__ W = blockIdx.x ? Wself : Wnbr;
  uint32_t* __restrict__ out = wt + (size_t)blockIdx.x * 8192;
  const int t = threadIdx.x;          // 256
  const int n = t >> 1, h = t & 1;
  for (int q = 0; q < 32; ++q) {
    int k2 = h * 32 + q;
    float lo = W[(2 * k2) * HD + n];
    float hi = W[(2 * k2 + 1) * HD + n];
    out[n * 64 + k2] = pk_bf16(lo, hi);
  }
}

// ---------------- K1: bucket edges by dst>>6 ----------------
__global__ void bucket_build(const int* __restrict__ ei, const float* __restrict__ ew,
                             int* __restrict__ cursors, uint2* __restrict__ buf) {
  int e = blockIdx.x * blockDim.x + threadIdx.x;
  if (e >= N_EDGES) return;
  int src = ei[e];
  int dst = ei[N_EDGES + e];
  float w = ew[e];
  int b = dst >> 6;
  int slot = atomicAdd(cursors + b, 1);
  if (slot < CAP)
    buf[(size_t)b * CAP + slot] =
        make_uint2(((uint32_t)src << 6) | (uint32_t)(dst & 63), __float_as_uint(w));
}

// ---------------- counts via binary search on sorted batch ----------------
__global__ void counts_kernel(const int* __restrict__ batch, float* __restrict__ counts) {
  int g = blockIdx.x * blockDim.x + threadIdx.x;
  if (g >= N_GRAPHS) return;
  int lo = 0, hi = N_NODES;
  while (lo < hi) { int mid = (lo + hi) >> 1; if (batch[mid] < g) lo = mid + 1; else hi = mid; }
  int s = lo; hi = N_NODES;
  while (lo < hi) { int mid = (lo + hi) >> 1; if (batch[mid] < g + 1) lo = mid + 1; else hi = mid; }
  counts[g] = (float)(lo - s);
}

// ------- K2: fused msg-build (LDS) + MFMA embed GEMM + mean-pool -------
// One block (8 waves, 512 thr) per bucket of 64 nodes. 48KB LDS:
//   [0,32K)   f32 msg accumulator [64][128] -> later C f32 [64][128]
//   [32K,48K) bf16 A-tile, 64 rows x 256B, 16B slot s at (s ^ (row&7))
__launch_bounds__(512, 4)
__global__ void embed_fused(const float* __restrict__ x,
                            const uint2* __restrict__ buf, const int* __restrict__ cursors,
                            const uint32_t* __restrict__ wt,
                            const float* __restrict__ bemb, const int* __restrict__ batch,
                            float* __restrict__ sums) {
  __shared__ float lds[12288];  // 48KB
  char* lb = (char*)lds;
  const int b = blockIdx.x;
  const int tid = threadIdx.x;
  const int node0 = b * BROWS;
  const int l = tid & 63, w = tid >> 6;
  const int wm = w >> 2, wn = w & 3;
  const int lr = l & 15, lk = l >> 4;

  // --- zero msg accumulator (32KB) ---
  {
    float4 z4 = make_float4(0.f, 0.f, 0.f, 0.f);
    float4* p = (float4*)lds;
    for (int i = tid; i < 2048; i += 512) p[i] = z4;
  }
  __syncthreads();

  // --- edge accumulation into LDS, software-pipelined ---
  {
    int cnt = cursors[b]; if (cnt > CAP) cnt = CAP;
    const uint2* eb = buf + (size_t)b * CAP;
    const int eg = tid >> 5;        // 16 groups of 32 lanes
    const int col = tid & 31;       // strided columns: col, col+32, col+64, col+96
    int e = eg;
    if (e < cnt) {
      const int cl = cnt - 1;
      uint2 pkA = eb[e];
      int i1 = e + 16; if (i1 > cl) i1 = cl;
      uint2 pkB = eb[i1];
      const float* xrA = x + ((size_t)(pkA.x >> 6)) * XD + col;
      float a0 = xrA[0], a1 = xrA[32], a2 = xrA[64], a3 = xrA[96];
      while (true) {
        int en = e + 16;
        int i2 = en + 16; if (i2 > cl) i2 = cl;
        uint2 pkC = eb[i2];
        const float* xrB = x + ((size_t)(pkB.x >> 6)) * XD + col;
        float b0 = xrB[0], b1 = xrB[32], b2 = xrB[64], b3 = xrB[96];
        float wgt = __uint_as_float(pkA.y);
        float* mp = lds + (pkA.x & 63u) * XD + col;
        atomicAdd(mp +  0, wgt * a0);
        atomicAdd(mp + 32, wgt * a1);
        atomicAdd(mp + 64, wgt * a2);
        atomicAdd(mp + 96, wgt * a3);
        e = en;
        if (e >= cnt) break;
        pkA = pkB; pkB = pkC;
        a0 = b0; a1 = b1; a2 = b2; a3 = b3;
      }
    }
  }
  __syncthreads();

  // --- convert msg f32 -> bf16 A-tile (disjoint LDS regions, single barrier after) ---
  {
    const int row = tid >> 3;     // 0..63
    const int c8 = tid & 7;       // 16 floats each
    const float* ar = lds + row * XD + c8 * 16;
    float v[16];
#pragma unroll
    for (int i = 0; i < 4; ++i) {
      int ii = (i + row) & 3;     // rotate to balance banks
      float4 t4 = *(const float4*)(ar + ii * 4);
      v[ii * 4 + 0] = t4.x; v[ii * 4 + 1] = t4.y; v[ii * 4 + 2] = t4.z; v[ii * 4 + 3] = t4.w;
    }
    uint32_t p[8];
#pragma unroll
    for (int i = 0; i < 8; ++i) p[i] = pk_bf16(v[2 * i], v[2 * i + 1]);
    char* aw = lb + 32768 + row * 256;
    const int s0 = c8 * 2;
    *(uint4*)(aw + (((s0)     ^ (row & 7)) << 4)) = make_uint4(p[0], p[1], p[2], p[3]);
    *(uint4*)(aw + (((s0 + 1) ^ (row & 7)) << 4)) = make_uint4(p[4], p[5], p[6], p[7]);
  }
  __syncthreads();

  f32x4 acc[2][2];
#pragma unroll
  for (int mf = 0; mf < 2; ++mf) { acc[mf][0] = (f32x4)0.f; acc[mf][1] = (f32x4)0.f; }

  // --- MFMA phase B: msg @ Wnbr (B-frags straight from global wt) ---
  {
    const char* wtb = (const char*)wt;
    bf16x8 bf[4][2];
#pragma unroll
    for (int kb = 0; kb < 4; ++kb)
#pragma unroll
      for (int nf = 0; nf < 2; ++nf) {
        int n = wn * 32 + nf * 16 + lr;
        bf[kb][nf] = *(const bf16x8*)(wtb + n * 256 + (kb << 6) + (lk << 4));
      }
#pragma unroll
    for (int kb = 0; kb < 4; ++kb) {
      int slot = (kb << 2) | lk;
#pragma unroll
      for (int mf = 0; mf < 2; ++mf) {
        int r = wm * 32 + mf * 16 + lr;
        bf16x8 a = *(const bf16x8*)(lb + 32768 + r * 256 + ((slot ^ (r & 7)) << 4));
        acc[mf][0] = __builtin_amdgcn_mfma_f32_16x16x32_bf16(a, bf[kb][0], acc[mf][0], 0, 0, 0);
        acc[mf][1] = __builtin_amdgcn_mfma_f32_16x16x32_bf16(a, bf[kb][1], acc[mf][1], 0, 0, 0);
      }
    }
  }
  __syncthreads();

  // --- restage A-tile = x rows (bf16) ---
  {
    const int row = tid >> 3;
    const int c8 = tid & 7;
    int m = node0 + row;
    int mc = m < N_NODES ? m : N_NODES - 1;
    const float* xr = x + (size_t)mc * XD + c8 * 16;
    uint32_t p[8];
#pragma unroll
    for (int i = 0; i < 4; ++i) {
      float4 t4 = *(const float4*)(xr + i * 4);
      p[2 * i]     = pk_bf16(t4.x, t4.y);
      p[2 * i + 1] = pk_bf16(t4.z, t4.w);
    }
    char* aw = lb + 32768 + row * 256;
    const int s0 = c8 * 2;
    *(uint4*)(aw + (((s0)     ^ (row & 7)) << 4)) = make_uint4(p[0], p[1], p[2], p[3]);
    *(uint4*)(aw + (((s0 + 1) ^ (row & 7)) << 4)) = make_uint4(p[4], p[5], p[6], p[7]);
  }
  __syncthreads();

  // --- MFMA phase A: x @ Wself ---
  {
    const char* wtb = (const char*)wt + 32768;
    bf16x8 bf[4][2];
#pragma unroll
    for (int kb = 0; kb < 4; ++kb)
#pragma unroll
      for (int nf = 0; nf < 2; ++nf) {
        int n = wn * 32 + nf * 16 + lr;
        bf[kb][nf] = *(const bf16x8*)(wtb + n * 256 + (kb << 6) + (lk << 4));
      }
#pragma unroll
    for (int kb = 0; kb < 4; ++kb) {
      int slot = (kb << 2) | lk;
#pragma unroll
      for (int mf = 0; mf < 2; ++mf) {
        int r = wm * 32 + mf * 16 + lr;
        bf16x8 a = *(const bf16x8*)(lb + 32768 + r * 256 + ((slot ^ (r & 7)) << 4));
        acc[mf][0] = __builtin_amdgcn_mfma_f32_16x16x32_bf16(a, bf[kb][0], acc[mf][0], 0, 0, 0);
        acc[mf][1] = __builtin_amdgcn_mfma_f32_16x16x32_bf16(a, bf[kb][1], acc[mf][1], 0, 0, 0);
      }
    }
  }

  // --- bias + relu, write C f32 [64][128] into [0,32K) (disjoint from A reads) ---
  {
    float be0 = bemb[wn * 32 + lr];
    float be1 = bemb[wn * 32 + 16 + lr];
#pragma unroll
    for (int mf = 0; mf < 2; ++mf)
#pragma unroll
      for (int r = 0; r < 4; ++r) {
        int row = wm * 32 + mf * 16 + lk * 4 + r;
        lds[row * XD + wn * 32 + lr]      = fmaxf(acc[mf][0][r] + be0, 0.f);
        lds[row * XD + wn * 32 + 16 + lr] = fmaxf(acc[mf][1][r] + be1, 0.f);
      }
  }
  __syncthreads();

  // --- segmented mean-pool: wave owns 8 consecutive sorted nodes (2/thread) ---
  {
    const int mg = tid >> 4;            // 0..31 -> rows 2mg, 2mg+1
    const int n0 = (tid & 15) << 3;
    const int lane = tid & 63;
    float av[2][8];
    int bg[2];
#pragma unroll
    for (int i = 0; i < 2; ++i) {
      int row = mg * 2 + i;
      int m = node0 + row;
      int mc = m < N_NODES ? m : N_NODES - 1;
      bg[i] = (m < N_NODES) ? batch[mc] : 0x7fffffff;
      float4 p0 = *(const float4*)&lds[row * XD + n0];
      float4 p1 = *(const float4*)&lds[row * XD + n0 + 4];
      av[i][0] = p0.x; av[i][1] = p0.y; av[i][2] = p0.z; av[i][3] = p0.w;
      av[i][4] = p1.x; av[i][5] = p1.y; av[i][6] = p1.z; av[i][7] = p1.w;
    }
    int g = __shfl(bg[0], 0, 64);
    while (g != 0x7fffffff) {
      float s[8];
#pragma unroll
      for (int j = 0; j < 8; ++j) s[j] = 0.f;
#pragma unroll
      for (int i = 0; i < 2; ++i) {
        bool m = (bg[i] == g);
#pragma unroll
        for (int j = 0; j < 8; ++j) s[j] += m ? av[i][j] : 0.f;
      }
#pragma unroll
      for (int j = 0; j < 8; ++j) {
        s[j] += __shfl_xor(s[j], 16, 64);
        s[j] += __shfl_xor(s[j], 32, 64);
      }
      if (lane < 16) {
        float* sp = sums + (size_t)g * HD + n0;
#pragma unroll
        for (int j = 0; j < 8; ++j) atomicAdd(sp + j, s[j]);
      }
      int nb = 0x7fffffff;
#pragma unroll
      for (int i = 0; i < 2; ++i)
        if (bg[i] > g && bg[i] < nb) nb = bg[i];
      for (int off = 1; off < 64; off <<= 1) {
        int o = __shfl_xor(nb, off, 64);
        nb = o < nb ? o : nb;
      }
      g = nb;
    }
  }
}

// ---------------- K4: head linear: aT[f][g] = h(g) @ W[:,f] + b ----------------
__global__ void head_kernel(const float* __restrict__ sums, const float* __restrict__ counts,
                            const float* __restrict__ y,
                            const float* __restrict__ Wmu, const float* __restrict__ bmu,
                            const float* __restrict__ Wvar, const float* __restrict__ bvar,
                            float* __restrict__ aT) {
  __shared__ float hrow[129];
  const int g = blockIdx.x;
  const int t = threadIdx.x;  // 128
  float cnt = fmaxf(counts[g], 1.f);
  hrow[t] = sums[(size_t)g * HD + t] / cnt;
  if (t == 0) hrow[128] = y[g];
  __syncthreads();
  const int head = t >> 6, n = t & 63;
  const float* __restrict__ W = head ? Wvar : Wmu;
  float acc = head ? bvar[n] : bmu[n];
  for (int k = 0; k < 129; ++k) acc = fmaf(hrow[k], W[k * ZD + n], acc);
  aT[(size_t)(head * ZD + n) * N_GRAPHS + g] = acc;
}

// ---------------- K5: BN stats per feature ----------------
__global__ void bnstats_kernel(const float* __restrict__ aT, float* __restrict__ stats) {
  const int f = blockIdx.x;  // 0..127
  const float* base = aT + (size_t)f * N_GRAPHS;
  float s = 0.f, ss = 0.f;
  for (int i = threadIdx.x; i < N_GRAPHS; i += 256) { float v = base[i]; s += v; ss += v * v; }
#pragma unroll
  for (int off = 1; off < 64; off <<= 1) { s += __shfl_xor(s, off, 64); ss += __shfl_xor(ss, off, 64); }
  __shared__ float ls[8];
  const int wav = threadIdx.x >> 6, lane = threadIdx.x & 63;
  if (lane == 0) { ls[wav * 2] = s; ls[wav * 2 + 1] = ss; }
  __syncthreads();
  if (threadIdx.x == 0) {
    float S = ls[0] + ls[2] + ls[4] + ls[6];
    float SS = ls[1] + ls[3] + ls[5] + ls[7];
    float mean = S / (float)N_GRAPHS;
    float var = SS / (float)N_GRAPHS - mean * mean;
    stats[f * 2] = mean;
    stats[f * 2 + 1] = rsqrtf(var + 1e-5f);
  }
}

// ---------------- K6: BN apply + relu (+sigmoid for var head) ----------------
__global__ void bnapply_kernel(const float* __restrict__ aT, const float* __restrict__ stats,
                               const float* __restrict__ gm, const float* __restrict__ btm,
                               const float* __restrict__ gv, const float* __restrict__ btv,
                               float* __restrict__ out) {
  int t = blockIdx.x * blockDim.x + threadIdx.x;
  if (t >= 2 * N_GRAPHS * ZD) return;
  int head = t >> 18;
  int r = t & (N_GRAPHS * ZD - 1);
  int g = r >> 6, n = r & 63;
  int f = (head << 6) | n;
  float v = aT[(size_t)f * N_GRAPHS + g];
  float z = (v - stats[f * 2]) * stats[f * 2 + 1];
  z = z * (head ? gv[n] : gm[n]) + (head ? btv[n] : btm[n]);
  z = fmaxf(z, 0.f);
  if (head) z = 1.f / (1.f + __expf(-z));
  out[t] = z;
}

extern "C" void kernel_launch(void* const* d_in, const int* in_sizes, int n_in,
                              void* d_out, int out_size, void* d_ws, size_t ws_size,
                              hipStream_t stream) {
  const float* x      = (const float*)d_in[0];
  const int*   ei     = (const int*)d_in[1];
  const float* ew     = (const float*)d_in[2];
  const float* y      = (const float*)d_in[3];
  const int*   batch  = (const int*)d_in[4];
  const float* Wself  = (const float*)d_in[5];
  const float* Wnbr   = (const float*)d_in[6];
  const float* bemb   = (const float*)d_in[7];
  const float* Wmu    = (const float*)d_in[8];
  const float* bmu    = (const float*)d_in[9];
  const float* gmu    = (const float*)d_in[10];
  const float* betamu = (const float*)d_in[11];
  const float* Wvar   = (const float*)d_in[12];
  const float* bvar   = (const float*)d_in[13];
  const float* gvar   = (const float*)d_in[14];
  const float* betavar= (const float*)d_in[15];

  float* ws       = (float*)d_ws;
  int*   cursors  = (int*)(ws + OFF_CUR);
  float* sums     = ws + OFF_SUMS;
  uint2* buf      = (uint2*)(ws + OFF_BUF);
  float* counts   = ws + OFF_CNT;
  float* aT       = ws + OFF_AT;
  float* stats    = ws + OFF_STATS;
  uint32_t* wt    = (uint32_t*)(ws + OFF_WT);

  // zero cursors + sums (~2.1MB, contiguous at ws base)
  hipMemsetAsync(ws, 0, (8192ull + 524288ull) * 4ull, stream);

  wprep_kernel<<<2, 256, 0, stream>>>(Wnbr, Wself, wt);
  bucket_build<<<(N_EDGES + 255) / 256, 256, 0, stream>>>(ei, ew, cursors, buf);
  counts_kernel<<<(N_GRAPHS + 255) / 256, 256, 0, stream>>>(batch, counts);
  embed_fused<<<NBUCKETS, 512, 0, stream>>>(x, buf, cursors, wt, bemb, batch, sums);
  head_kernel<<<N_GRAPHS, 128, 0, stream>>>(sums, counts, y, Wmu, bmu, Wvar, bvar, aT);
  bnstats_kernel<<<128, 256, 0, stream>>>(aT, stats);
  bnapply_kernel<<<(2 * N_GRAPHS * ZD + 255) / 256, 256, 0, stream>>>(
      aT, stats, gmu, betamu, gvar, betavar, (float*)d_out);
}